// Round 5
// baseline (326.022 us; speedup 1.0000x reference)
//
#include <hip/hip_runtime.h>
#include <hip/hip_bf16.h>

#define B_EV    8192
#define R_NEG   32
#define DIM     256
#define K_COM   5
#define M_ROWS  (B_EV * (R_NEG + 2))   // 278528
#define BM      64
#define NT      (M_ROWS / BM)          // 4352 row-tiles
#define NBLK    512                    // persistent grid: 2 blocks/CU x 256 CU
#define N_NODES_C 100000

typedef _Float16 f16x8 __attribute__((ext_vector_type(8)));
typedef float    f32x4 __attribute__((ext_vector_type(4)));

// Persistent-block fused kernel.
//  Once per block: load this wave's 32 W1 B-fragments (f16) into VGPRs
//  (128 VGPR). Then grid-stride over 64-row tiles:
//   gather nodes/gates -> stage X tile (f16, XOR-swizzled LDS) -> 8x16 MFMA
//   (B from regs, zero W1 staging, 3 barriers/tile) -> VALU epilogue
//   relu(h+b1)@W2 -> cross-wave reduce -> softmax -> scatter.
// Fragment layouts proven by round-3 pass:
//   A-frag: lane holds A[row=l15][k=8g+j]; B-frag: B[k=8g+j][col=l15];
//   C/D:    lane holds D[row=4g+reg][col=l15].
__global__ __launch_bounds__(256, 2) void fused_kernel(
    const int* __restrict__ src, const int* __restrict__ dst,
    const int* __restrict__ neg, const float* __restrict__ ts,
    const float* __restrict__ state, const float* __restrict__ last_t,
    const float* __restrict__ log_decay,
    const float* __restrict__ W1, const float* __restrict__ b1,
    const float* __restrict__ W2, const float* __restrict__ b2,
    float* __restrict__ out)
{
    __shared__ f16x8 xt8[2048];            // 32 KB X tile [row][chunk^(row&7)]
    __shared__ int   node_s[64];
    __shared__ float gate_s[64];
    __shared__ float part[4][64][K_COM];   // 5 KB cross-wave partials

    const int tid  = threadIdx.x;
    const int lane = tid & 63;
    const int w    = tid >> 6;      // wave 0..3, owns h-cols w*64..w*64+63
    const int l15  = lane & 15;
    const int g    = lane >> 4;

    float ld    = log_decay[0];
    float decay = (ld > 30.f) ? ld : log1pf(expf(ld));   // stable softplus

    // ---- one-time: W1 B-fragments into registers (128 VGPR) ----
    // bfrag[nt][ks][j] = W1[k = ks*32 + g*8 + j][col = w*64 + nt*16 + l15]
    f16x8 bfrag[4][8];
    {
        const float* wbase = W1 + (size_t)(g * 8) * DIM + w * 64 + l15;
        #pragma unroll
        for (int nt = 0; nt < 4; ++nt)
            #pragma unroll
            for (int ks = 0; ks < 8; ++ks)
                #pragma unroll
                for (int j = 0; j < 8; ++j)
                    bfrag[nt][ks][j] = (_Float16)wbase[(size_t)(ks * 32 + j) * DIM + nt * 16];
    }

    // ---- persistent loop over row-tiles ----
    for (int t = blockIdx.x; t < NT; t += NBLK) {
        const int m0 = t * BM;

        if (tid < 64) {
            int m  = m0 + tid;
            int be = m / 34;
            int sl = m - be * 34;
            int node = (sl == 0) ? src[be] : (sl == 1) ? dst[be] : neg[be * R_NEG + (sl - 2)];
            if ((unsigned)node >= (unsigned)N_NODES_C) node = 0;
            float dtv = fmaxf(ts[be] - last_t[node], 0.f);
            node_s[tid] = node;
            gate_s[tid] = expf(-decay * dtv);
        }
        __syncthreads();   // barrier 1: node/gate visible

        // Stage X tile: 64 rows x 256 cols f16, gate applied, XOR-swizzled.
        {
            int c8 = tid & 31;
            int rb = tid >> 5;
            #pragma unroll
            for (int it = 0; it < 8; ++it) {
                int r = it * 8 + rb;
                int node = node_s[r];
                float gg = gate_s[r];
                const float* sp = state + (size_t)node * DIM + c8 * 8;
                float4 v0 = *(const float4*)(sp);
                float4 v1 = *(const float4*)(sp + 4);
                f16x8 pk;
                pk[0] = (_Float16)(v0.x * gg); pk[1] = (_Float16)(v0.y * gg);
                pk[2] = (_Float16)(v0.z * gg); pk[3] = (_Float16)(v0.w * gg);
                pk[4] = (_Float16)(v1.x * gg); pk[5] = (_Float16)(v1.y * gg);
                pk[6] = (_Float16)(v1.z * gg); pk[7] = (_Float16)(v1.w * gg);
                xt8[(r * 32 + c8) ^ (r & 7)] = pk;
            }
        }
        __syncthreads();   // barrier 2: X tile visible

        f32x4 acc[4][4];
        #pragma unroll
        for (int a = 0; a < 4; ++a)
            #pragma unroll
            for (int bb = 0; bb < 4; ++bb)
                acc[a][bb] = (f32x4){0.f, 0.f, 0.f, 0.f};

        #pragma unroll
        for (int ks = 0; ks < 8; ++ks) {
            f16x8 av[4];
            #pragma unroll
            for (int mt = 0; mt < 4; ++mt) {
                int row = mt * 16 + l15;
                av[mt] = xt8[(row * 32 + ks * 4 + g) ^ (row & 7)];
            }
            #pragma unroll
            for (int nt = 0; nt < 4; ++nt)
                #pragma unroll
                for (int mt = 0; mt < 4; ++mt)
                    acc[mt][nt] = __builtin_amdgcn_mfma_f32_16x16x32_f16(av[mt], bfrag[nt][ks], acc[mt][nt], 0, 0, 0);
        }

        // Epilogue: relu(h+b1)@W2, 16-lane shfl reduce, cross-wave partials.
        float b1v[4];
        float w2v[4][K_COM];
        #pragma unroll
        for (int nt = 0; nt < 4; ++nt) {
            int col = w * 64 + nt * 16 + l15;
            b1v[nt] = b1[col];
            #pragma unroll
            for (int k = 0; k < K_COM; ++k) w2v[nt][k] = W2[col * K_COM + k];
        }

        #pragma unroll
        for (int mt = 0; mt < 4; ++mt) {
            #pragma unroll
            for (int reg = 0; reg < 4; ++reg) {
                float p[K_COM] = {0.f, 0.f, 0.f, 0.f, 0.f};
                #pragma unroll
                for (int nt = 0; nt < 4; ++nt) {
                    float h = fmaxf(acc[mt][nt][reg] + b1v[nt], 0.f);
                    #pragma unroll
                    for (int k = 0; k < K_COM; ++k) p[k] += h * w2v[nt][k];
                }
                #pragma unroll
                for (int off = 8; off >= 1; off >>= 1)
                    #pragma unroll
                    for (int k = 0; k < K_COM; ++k) p[k] += __shfl_xor(p[k], off);
                if (l15 == 0) {
                    int row = mt * 16 + g * 4 + reg;
                    #pragma unroll
                    for (int k = 0; k < K_COM; ++k) part[w][row][k] = p[k];
                }
            }
        }
        __syncthreads();   // barrier 3: partials visible

        if (tid < 64) {
            float lg[K_COM];
            #pragma unroll
            for (int k = 0; k < K_COM; ++k)
                lg[k] = part[0][tid][k] + part[1][tid][k] + part[2][tid][k] + part[3][tid][k] + b2[k];
            float mx = lg[0];
            #pragma unroll
            for (int k = 1; k < K_COM; ++k) mx = fmaxf(mx, lg[k]);
            float sum = 0.f;
            #pragma unroll
            for (int k = 0; k < K_COM; ++k) { lg[k] = expf(lg[k] - mx); sum += lg[k]; }
            float inv = 1.f / sum;

            int m  = m0 + tid;
            int be = m / 34;
            int sl = m - be * 34;
            float* op;
            if (sl == 0)      op = out + (size_t)be * K_COM;
            else if (sl == 1) op = out + (size_t)B_EV * K_COM + (size_t)be * K_COM;
            else              op = out + (size_t)2 * B_EV * K_COM + ((size_t)be * R_NEG + (sl - 2)) * K_COM;
            #pragma unroll
            for (int k = 0; k < K_COM; ++k) op[k] = lg[k] * inv;
        }
        // next iteration's barrier 1 protects part[] / xt8 reuse
    }
}

extern "C" void kernel_launch(void* const* d_in, const int* in_sizes, int n_in,
                              void* d_out, int out_size, void* d_ws, size_t ws_size,
                              hipStream_t stream) {
    const int*   src       = (const int*)d_in[0];
    const int*   dst       = (const int*)d_in[1];
    const int*   neg       = (const int*)d_in[2];
    const float* ts        = (const float*)d_in[3];
    // d_in[4] = edge_idxs (unused by the reference)
    const float* state     = (const float*)d_in[5];
    const float* last_t    = (const float*)d_in[6];
    const float* log_decay = (const float*)d_in[7];
    const float* W1        = (const float*)d_in[8];
    const float* b1        = (const float*)d_in[9];
    const float* W2        = (const float*)d_in[10];
    const float* b2        = (const float*)d_in[11];

    fused_kernel<<<dim3(NBLK), dim3(256), 0, stream>>>(
        src, dst, neg, ts, state, last_t, log_decay, W1, b1, W2, b2,
        (float*)d_out);
}